// Round 3
// baseline (416.448 us; speedup 1.0000x reference)
//
#include <hip/hip_runtime.h>
#include <hip/hip_bf16.h>

#define D_FEAT 64

// ---------- CSR-build path (no float atomics) ----------

// Zero the count/cursor arrays (2*n_nodes+1 ints).
__global__ void mp_zero_kernel(int* __restrict__ p, int n) {
    int i = blockIdx.x * blockDim.x + threadIdx.x;
    if (i < n) p[i] = 0;
}

// Histogram of destination indices into start[d+1].
__global__ void mp_hist_kernel(const int* __restrict__ edst,
                               int* __restrict__ start, int n_edges) {
    int e = blockIdx.x * blockDim.x + threadIdx.x;
    if (e < n_edges) atomicAdd(&start[edst[e] + 1], 1);
}

// Single-block inclusive scan, in place. n up to ~100001.
// 1024 threads; each owns a contiguous chunk.
__global__ void mp_scan_kernel(int* __restrict__ a, int n) {
    __shared__ int sums[1024];
    int t = threadIdx.x;
    int chunk = (n + 1023) / 1024;
    int lo = t * chunk, hi = min(n, lo + chunk);
    int s = 0;
    for (int i = lo; i < hi; ++i) s += a[i];
    sums[t] = s;
    __syncthreads();
    // Hillis-Steele inclusive scan over 1024 partial sums
    for (int off = 1; off < 1024; off <<= 1) {
        int v = (t >= off) ? sums[t - off] : 0;
        __syncthreads();
        sums[t] += v;
        __syncthreads();
    }
    int run = (t == 0) ? 0 : sums[t - 1];   // exclusive prefix of this chunk
    for (int i = lo; i < hi; ++i) {
        run += a[i];
        a[i] = run;
    }
}

// Scatter edges into CSR order: elist[start[d]+cursor[d]++] = {src, weight}
__global__ void mp_csr_scatter_kernel(const int* __restrict__ esrc,
                                      const int* __restrict__ edst,
                                      const float* __restrict__ ew,
                                      const int* __restrict__ start,
                                      int* __restrict__ cursor,
                                      int2* __restrict__ elist, int n_edges) {
    int e = blockIdx.x * blockDim.x + threadIdx.x;
    if (e >= n_edges) return;
    int d = edst[e];
    int pos = start[d] + atomicAdd(&cursor[d], 1);
    elist[pos] = make_int2(esrc[e], __float_as_int(ew[e]));
}

// One wave per destination node; lane = feature. Register accumulate, single write.
__global__ void mp_gather_kernel(const float* __restrict__ input,
                                 const int* __restrict__ start,
                                 const int2* __restrict__ elist,
                                 float* __restrict__ out, int n_nodes) {
    int wid = (blockIdx.x * blockDim.x + threadIdx.x) >> 6;
    if (wid >= n_nodes) return;
    int lane = threadIdx.x & 63;
    int b = start[wid], e_end = start[wid + 1];
    float acc = input[(long long)wid * D_FEAT + lane];
    int i = b;
    for (; i + 1 < e_end; i += 2) {       // 2-way unroll for memory-level parallelism
        int2 e0 = elist[i];
        int2 e1 = elist[i + 1];
        float v0 = input[(long long)e0.x * D_FEAT + lane];
        float v1 = input[(long long)e1.x * D_FEAT + lane];
        acc += v0 * __int_as_float(e0.y);
        acc += v1 * __int_as_float(e1.y);
    }
    if (i < e_end) {
        int2 e0 = elist[i];
        acc += input[(long long)e0.x * D_FEAT + lane] * __int_as_float(e0.y);
    }
    out[(long long)wid * D_FEAT + lane] = acc;
}

// ---------- fallback path (atomic scatter) if ws too small ----------

__global__ void mp_copy_kernel(const float4* __restrict__ in,
                               float4* __restrict__ out, int n4) {
    int i = blockIdx.x * blockDim.x + threadIdx.x;
    if (i < n4) out[i] = in[i];
}

__global__ void mp_scatter_kernel(const float* __restrict__ input,
                                  const float* __restrict__ ew,
                                  const int* __restrict__ esrc,
                                  const int* __restrict__ edst,
                                  float* __restrict__ out, int n_edges) {
    int tid = blockIdx.x * blockDim.x + threadIdx.x;
    int e = tid >> 6;
    if (e >= n_edges) return;
    int lane = tid & 63;
    float v = input[(long long)esrc[e] * D_FEAT + lane] * ew[e];
    atomicAdd(&out[(long long)edst[e] * D_FEAT + lane], v);
}

extern "C" void kernel_launch(void* const* d_in, const int* in_sizes, int n_in,
                              void* d_out, int out_size, void* d_ws, size_t ws_size,
                              hipStream_t stream) {
    const float* input = (const float*)d_in[0];
    const float* ew    = (const float*)d_in[1];
    const int* esrc    = (const int*)d_in[2];
    const int* edst    = (const int*)d_in[3];
    float* out = (float*)d_out;

    int n_nodes = in_sizes[0] / D_FEAT;   // 100000
    int n_edges = in_sizes[1];            // 1600000

    // ws layout: start[n_nodes+1] | cursor[n_nodes] | pad to 256 | elist[n_edges] (int2)
    size_t ints = (size_t)(2 * n_nodes + 1);
    size_t elist_off = (ints * 4 + 255) & ~(size_t)255;
    size_t needed = elist_off + (size_t)n_edges * 8;

    if (ws_size >= needed) {
        int* start  = (int*)d_ws;
        int* cursor = start + (n_nodes + 1);
        int2* elist = (int2*)((char*)d_ws + elist_off);

        int nz = 2 * n_nodes + 1;
        mp_zero_kernel<<<(nz + 255) / 256, 256, 0, stream>>>(start, nz);
        mp_hist_kernel<<<(n_edges + 255) / 256, 256, 0, stream>>>(edst, start, n_edges);
        mp_scan_kernel<<<1, 1024, 0, stream>>>(start, n_nodes + 1);
        mp_csr_scatter_kernel<<<(n_edges + 255) / 256, 256, 0, stream>>>(
            esrc, edst, ew, start, cursor, elist, n_edges);
        long long total = (long long)n_nodes * 64;
        mp_gather_kernel<<<(int)((total + 255) / 256), 256, 0, stream>>>(
            input, start, elist, out, n_nodes);
    } else {
        // fallback: atomic scatter
        int n4 = (n_nodes * D_FEAT) / 4;
        mp_copy_kernel<<<(n4 + 255) / 256, 256, 0, stream>>>(
            (const float4*)input, (float4*)out, n4);
        long long total = (long long)n_edges * 64;
        mp_scatter_kernel<<<(int)((total + 255) / 256), 256, 0, stream>>>(
            input, ew, esrc, edst, out, n_edges);
    }
}

// Round 4
// 280.046 us; speedup vs baseline: 1.4871x; 1.4871x over previous
//
#include <hip/hip_runtime.h>
#include <hip/hip_bf16.h>

#define D_FEAT 64
#define SCAN_T 256
#define SCAN_PER_T 8
#define SCAN_CHUNK (SCAN_T * SCAN_PER_T)   // 2048

// Zero the count/cursor arrays (2*n_nodes+1 ints).
__global__ void mp_zero_kernel(int* __restrict__ p, int n) {
    int i = blockIdx.x * blockDim.x + threadIdx.x;
    if (i < n) p[i] = 0;
}

// Histogram of destination indices into start[d+1].
__global__ void mp_hist_kernel(const int* __restrict__ edst,
                               int* __restrict__ start, int n_edges) {
    int e = blockIdx.x * blockDim.x + threadIdx.x;
    if (e < n_edges) atomicAdd(&start[edst[e] + 1], 1);
}

// Multi-block scan, stage 1: per-block inclusive scan of a 2048-elem chunk,
// block sum -> partials[blockIdx].
__global__ void mp_scan1_kernel(int* __restrict__ a, int* __restrict__ partials, int n) {
    __shared__ int tsum[SCAN_T];
    int t = threadIdx.x;
    int base = blockIdx.x * SCAN_CHUNK + t * SCAN_PER_T;
    int v[SCAN_PER_T];
    int s = 0;
    #pragma unroll
    for (int j = 0; j < SCAN_PER_T; ++j) {
        int idx = base + j;
        v[j] = (idx < n) ? a[idx] : 0;
        s += v[j];
    }
    tsum[t] = s;
    __syncthreads();
    // Hillis-Steele inclusive scan over 256 thread-sums
    #pragma unroll
    for (int off = 1; off < SCAN_T; off <<= 1) {
        int u = (t >= off) ? tsum[t - off] : 0;
        __syncthreads();
        tsum[t] += u;
        __syncthreads();
    }
    if (t == SCAN_T - 1) partials[blockIdx.x] = tsum[t];
    int run = (t == 0) ? 0 : tsum[t - 1];
    #pragma unroll
    for (int j = 0; j < SCAN_PER_T; ++j) {
        int idx = base + j;
        run += v[j];
        if (idx < n) a[idx] = run;
    }
}

// Stage 2: single-wave inclusive scan of nb (<=64) block partials, in place.
__global__ void mp_scan2_kernel(int* __restrict__ partials, int nb) {
    int lane = threadIdx.x;   // blockDim.x == 64
    int v = (lane < nb) ? partials[lane] : 0;
    #pragma unroll
    for (int off = 1; off < 64; off <<= 1) {
        int u = __shfl_up(v, off, 64);
        if (lane >= off) v += u;
    }
    if (lane < nb) partials[lane] = v;
}

// Stage 3: add scanned partial of preceding blocks to each chunk.
__global__ void mp_scan3_kernel(int* __restrict__ a, const int* __restrict__ partials, int n) {
    int b = blockIdx.x;
    if (b == 0) return;
    int off = partials[b - 1];
    int base = b * SCAN_CHUNK + threadIdx.x * SCAN_PER_T;
    #pragma unroll
    for (int j = 0; j < SCAN_PER_T; ++j) {
        int idx = base + j;
        if (idx < n) a[idx] += off;
    }
}

// Scatter edges into CSR order: elist[start[d]+cursor[d]++] = {src, weight}
__global__ void mp_csr_scatter_kernel(const int* __restrict__ esrc,
                                      const int* __restrict__ edst,
                                      const float* __restrict__ ew,
                                      const int* __restrict__ start,
                                      int* __restrict__ cursor,
                                      int2* __restrict__ elist, int n_edges) {
    int e = blockIdx.x * blockDim.x + threadIdx.x;
    if (e >= n_edges) return;
    int d = edst[e];
    int pos = start[d] + atomicAdd(&cursor[d], 1);
    elist[pos] = make_int2(esrc[e], __float_as_int(ew[e]));
}

// One wave per destination node; lane = feature. Register accumulate, single write.
__global__ void mp_gather_kernel(const float* __restrict__ input,
                                 const int* __restrict__ start,
                                 const int2* __restrict__ elist,
                                 float* __restrict__ out, int n_nodes) {
    int wid = (blockIdx.x * blockDim.x + threadIdx.x) >> 6;
    if (wid >= n_nodes) return;
    int lane = threadIdx.x & 63;
    int b = start[wid], e_end = start[wid + 1];
    float acc = input[(long long)wid * D_FEAT + lane];
    int i = b;
    for (; i + 1 < e_end; i += 2) {       // 2-way unroll for memory-level parallelism
        int2 e0 = elist[i];
        int2 e1 = elist[i + 1];
        float v0 = input[(long long)e0.x * D_FEAT + lane];
        float v1 = input[(long long)e1.x * D_FEAT + lane];
        acc += v0 * __int_as_float(e0.y);
        acc += v1 * __int_as_float(e1.y);
    }
    if (i < e_end) {
        int2 e0 = elist[i];
        acc += input[(long long)e0.x * D_FEAT + lane] * __int_as_float(e0.y);
    }
    out[(long long)wid * D_FEAT + lane] = acc;
}

// ---------- fallback path (atomic scatter) if ws too small ----------

__global__ void mp_copy_kernel(const float4* __restrict__ in,
                               float4* __restrict__ out, int n4) {
    int i = blockIdx.x * blockDim.x + threadIdx.x;
    if (i < n4) out[i] = in[i];
}

__global__ void mp_scatter_kernel(const float* __restrict__ input,
                                  const float* __restrict__ ew,
                                  const int* __restrict__ esrc,
                                  const int* __restrict__ edst,
                                  float* __restrict__ out, int n_edges) {
    int tid = blockIdx.x * blockDim.x + threadIdx.x;
    int e = tid >> 6;
    if (e >= n_edges) return;
    int lane = tid & 63;
    float v = input[(long long)esrc[e] * D_FEAT + lane] * ew[e];
    atomicAdd(&out[(long long)edst[e] * D_FEAT + lane], v);
}

extern "C" void kernel_launch(void* const* d_in, const int* in_sizes, int n_in,
                              void* d_out, int out_size, void* d_ws, size_t ws_size,
                              hipStream_t stream) {
    const float* input = (const float*)d_in[0];
    const float* ew    = (const float*)d_in[1];
    const int* esrc    = (const int*)d_in[2];
    const int* edst    = (const int*)d_in[3];
    float* out = (float*)d_out;

    int n_nodes = in_sizes[0] / D_FEAT;   // 100000
    int n_edges = in_sizes[1];            // 1600000

    int n_scan = n_nodes + 1;
    int nb = (n_scan + SCAN_CHUNK - 1) / SCAN_CHUNK;   // 49 for 100001

    // ws layout: start[n+1] | cursor[n] | partials[nb] | pad256 | elist[E] (int2)
    size_t ints = (size_t)(2 * n_nodes + 1 + nb);
    size_t elist_off = (ints * 4 + 255) & ~(size_t)255;
    size_t needed = elist_off + (size_t)n_edges * 8;

    if (ws_size >= needed && nb <= 64) {
        int* start    = (int*)d_ws;
        int* cursor   = start + (n_nodes + 1);
        int* partials = cursor + n_nodes;
        int2* elist   = (int2*)((char*)d_ws + elist_off);

        int nz = 2 * n_nodes + 1;
        mp_zero_kernel<<<(nz + 255) / 256, 256, 0, stream>>>(start, nz);
        mp_hist_kernel<<<(n_edges + 255) / 256, 256, 0, stream>>>(edst, start, n_edges);
        mp_scan1_kernel<<<nb, SCAN_T, 0, stream>>>(start, partials, n_scan);
        mp_scan2_kernel<<<1, 64, 0, stream>>>(partials, nb);
        mp_scan3_kernel<<<nb, SCAN_T, 0, stream>>>(start, partials, n_scan);
        mp_csr_scatter_kernel<<<(n_edges + 255) / 256, 256, 0, stream>>>(
            esrc, edst, ew, start, cursor, elist, n_edges);
        long long total = (long long)n_nodes * 64;
        mp_gather_kernel<<<(int)((total + 255) / 256), 256, 0, stream>>>(
            input, start, elist, out, n_nodes);
    } else {
        // fallback: atomic scatter
        int n4 = (n_nodes * D_FEAT) / 4;
        mp_copy_kernel<<<(n4 + 255) / 256, 256, 0, stream>>>(
            (const float4*)input, (float4*)out, n4);
        long long total = (long long)n_edges * 64;
        mp_scatter_kernel<<<(int)((total + 255) / 256), 256, 0, stream>>>(
            input, ew, esrc, edst, out, n_edges);
    }
}